// Round 1
// baseline (106681.006 us; speedup 1.0000x reference)
//
#include <hip/hip_runtime.h>
#include <cstdint>
#include <cstddef>

#define TT   512
#define NWG  256
#define SLOT 65536            // floats per timestep slot in d_out
#define SLOTB 262144          // bytes per slot
#define FINALOFF ((size_t)TT * (size_t)SLOT)

// ws layout (bytes)
#define OFF_M     0                         // M fp16: 1024*1024*2 = 2 MiB
#define OFF_H0    2097152                   // 64*1024 f16
#define OFF_TH0   (OFF_H0 + 131072)
#define OFF_H1    (OFF_TH0 + 131072)
#define OFF_TH    (OFF_H1 + 131072)
#define OFF_B0    (OFF_TH + 131072)         // 1024 f32
#define OFF_C1    (OFF_B0 + 4096)           // 1024 f32
#define OFF_FLAGS (OFF_C1 + 4096)           // 512 uints (flags[0..255], gen at [320])

typedef _Float16 f16;
typedef _Float16 h2 __attribute__((ext_vector_type(2)));

#if __has_builtin(__builtin_amdgcn_fdot2)
__device__ __forceinline__ float fdot2(unsigned int a, unsigned int w, float c) {
  return __builtin_amdgcn_fdot2(__builtin_bit_cast(h2, a), __builtin_bit_cast(h2, w), c, false);
}
#else
__device__ __forceinline__ float fdot2(unsigned int a, unsigned int w, float c) {
  h2 ha = __builtin_bit_cast(h2, a), hw = __builtin_bit_cast(h2, w);
  return c + (float)ha.x * (float)hw.x + (float)ha.y * (float)hw.y;
}
#endif

__global__ void k_init(unsigned int* flags) {
  flags[threadIdx.x] = 0u;  // 512 threads cover flags + gen
}

// c1[i] = sum_k Wi1[i,k]*bo0[k] + bi1[i] + bh1[i];  b0[i] = bi0[i] + bh0[i]
__global__ void k_bias_c1(const float* __restrict__ Wi, const float* __restrict__ bi,
                          const float* __restrict__ bh, const float* __restrict__ bo,
                          float* __restrict__ b0, float* __restrict__ c1) {
  const int i = blockIdx.x * 256 + threadIdx.x;
  const float* row = Wi + 1048576 + (size_t)i * 1024;
  float s = 0.f;
  for (int k = 0; k < 1024; k += 4) {
    const float4 w = *(const float4*)&row[k];
    const float4 v = *(const float4*)&bo[k];
    s += w.x * v.x + w.y * v.y + w.z * v.z + w.w * v.w;
  }
  c1[i] = s + bi[1024 + i] + bh[1024 + i];
  b0[i] = bi[i] + bh[i];
}

// M[i][d] = sum_k Wi1[i][k] * Wo0[k][d]   (fp32 compute, fp16 store)
__global__ __launch_bounds__(256) void k_gemm_M(const float* __restrict__ Wi,
                                                const float* __restrict__ Wo,
                                                f16* __restrict__ Mh) {
  const float* A = Wi + 1048576;  // [i][k]
  const float* B = Wo;            // [k][d]
  __shared__ float As[16][68];
  __shared__ float Bs[16][68];
  const int bi = blockIdx.x >> 4, bj = blockIdx.x & 15;
  const int i0 = bi * 64, d0 = bj * 64;
  const int ti = threadIdx.x >> 4, tj = threadIdx.x & 15;
  float acc[4][4] = {};
  for (int kc = 0; kc < 1024; kc += 16) {
    const int r = threadIdx.x >> 2, cg = (threadIdx.x & 3) << 2;
    const float4 av = *(const float4*)&A[(size_t)(i0 + r) * 1024 + kc + cg];
    As[cg + 0][r] = av.x; As[cg + 1][r] = av.y; As[cg + 2][r] = av.z; As[cg + 3][r] = av.w;
    const int c2 = threadIdx.x >> 4, dg = (threadIdx.x & 15) << 2;
    const float4 bv = *(const float4*)&B[(size_t)(kc + c2) * 1024 + d0 + dg];
    *(float4*)&Bs[c2][dg] = bv;
    __syncthreads();
#pragma unroll
    for (int kk = 0; kk < 16; ++kk) {
      float a[4], b[4];
#pragma unroll
      for (int q = 0; q < 4; ++q) { a[q] = As[kk][ti * 4 + q]; b[q] = Bs[kk][tj * 4 + q]; }
#pragma unroll
      for (int p = 0; p < 4; ++p)
#pragma unroll
        for (int q = 0; q < 4; ++q) acc[p][q] += a[p] * b[q];
    }
    __syncthreads();
  }
#pragma unroll
  for (int p = 0; p < 4; ++p)
#pragma unroll
    for (int q = 0; q < 4; ++q)
      Mh[(size_t)(i0 + ti * 4 + p) * 1024 + (size_t)(d0 + tj * 4 + q)] = (f16)acc[p][q];
}

// x (fp32) -> fp16 copies stored in the first half of each d_out timestep slot
__global__ void k_convert_x(const float* __restrict__ x, float* __restrict__ dout) {
  const size_t idx4 = (size_t)blockIdx.x * 256 + threadIdx.x;
  const int t = (int)(idx4 >> 14);
  const int r = (int)(idx4 & 16383);
  const float4 v = ((const float4*)x)[idx4];
  f16* dst = (f16*)((char*)dout + (size_t)t * SLOTB) + (size_t)r * 4;
  dst[0] = (f16)v.x; dst[1] = (f16)v.y; dst[2] = (f16)v.z; dst[3] = (f16)v.w;
}

// ---- grid barrier: per-WG flag + WG0 master poll + gen release ----
__device__ __forceinline__ void gbar(unsigned int* flags, unsigned int* gen, int wg, unsigned int ph) {
  __threadfence();
  __syncthreads();
  if (wg == 0) {
    const int tt = threadIdx.x;
    if (tt > 0 && tt < NWG) {
      while (__hip_atomic_load(&flags[tt], __ATOMIC_ACQUIRE, __HIP_MEMORY_SCOPE_AGENT) < ph) {
        __builtin_amdgcn_s_sleep(1);
      }
    }
    __syncthreads();
    if (tt == 0) {
      __hip_atomic_store(gen, ph, __ATOMIC_RELEASE, __HIP_MEMORY_SCOPE_AGENT);
    }
  } else {
    if (threadIdx.x == 0) {
      __hip_atomic_store(&flags[wg], ph, __ATOMIC_RELEASE, __HIP_MEMORY_SCOPE_AGENT);
      while (__hip_atomic_load(gen, __ATOMIC_ACQUIRE, __HIP_MEMORY_SCOPE_AGENT) < ph) {
        __builtin_amdgcn_s_sleep(1);
      }
    }
    __syncthreads();
  }
}

// ---- persistent RNN loop ----
// WG = (bg = wg&1 : 32 batch rows, js = wg>>1 : 8 output rows)
// phase A(t): h0 = Wi0*x[t] + Wh0*th + b0 ; outs[t-1] = Wo1*h1 + bo1
// phase B(t): h1 = M*h0 + Wh1*th0 + c1 ; th = tanh(h1)
__global__ __launch_bounds__(1024, 4) void k_rnn(
    const float* __restrict__ Wi, const float* __restrict__ Wh,
    const float* __restrict__ Wo, const float* __restrict__ bo,
    char* __restrict__ ws, float* __restrict__ dout)
{
  const f16* Mh  = (const f16*)(ws + OFF_M);
  f16* h0h  = (f16*)(ws + OFF_H0);
  f16* th0h = (f16*)(ws + OFF_TH0);
  f16* h1h  = (f16*)(ws + OFF_H1);
  f16* thh  = (f16*)(ws + OFF_TH);
  const float* b0 = (const float*)(ws + OFF_B0);
  const float* c1 = (const float*)(ws + OFF_C1);
  unsigned int* flags = (unsigned int*)(ws + OFF_FLAGS);
  unsigned int* gen = flags + 320;

  const int wg = blockIdx.x;
  const int bg = wg & 1;
  const int js = wg >> 1;
  const int tid = threadIdx.x;
  const int b5 = tid & 31;
  const int ks = tid >> 5;  // 0..31 (K split)

  __shared__ __align__(16) f16 Wl[5 * 8 * 1032];   // 5 mats x 8 rows, padded stride
  __shared__ __align__(16) char shbuf[50688];      // act chunks / reduction (overlaid)
  f16* sa = (f16*)shbuf;
  float* sr = (float*)shbuf;

  // load + convert this WG's weight rows into LDS (mats: 0 Wi0, 1 Wh0, 2 M, 3 Wh1, 4 Wo1)
  for (int u = tid; u < 5 * 2048; u += 1024) {
    const int m = u >> 11;
    const int rr = (u >> 8) & 7;
    const int cc = (u & 255) << 2;
    const int grow = js * 8 + rr;
    f16* dst = &Wl[(m * 8 + rr) * 1032 + cc];
    if (m == 2) {
      *(uint2*)dst = *(const uint2*)&Mh[(size_t)grow * 1024 + cc];
    } else {
      const float* s = (m == 0) ? Wi : (m == 1) ? Wh : (m == 3) ? (Wh + 1048576) : (Wo + 1048576);
      const float4 v = *(const float4*)&s[(size_t)grow * 1024 + cc];
      dst[0] = (f16)v.x; dst[1] = (f16)v.y; dst[2] = (f16)v.z; dst[3] = (f16)v.w;
    }
  }
  float bias_b0 = 0.f, bias_c1 = 0.f, bias_bo1 = 0.f;
  if (tid < 256) {
    const int gj = js * 8 + (tid >> 5);
    bias_b0 = b0[gj]; bias_c1 = c1[gj]; bias_bo1 = bo[1024 + gj];
  }
  __syncthreads();

  const size_t rowbase = (size_t)(bg * 32) * 1024;
  unsigned int ph = 0;

  for (int t = 0; t <= TT; ++t) {
    const bool do_h0 = (t < TT);
    const bool do_rec = (t > 0);
    const f16* xh = (const f16*)((const char*)dout + (size_t)t * SLOTB);

    float acc0[8] = {0,0,0,0,0,0,0,0};
    float acc1[8] = {0,0,0,0,0,0,0,0};

    for (int c = 0; c < 4; ++c) {
      __syncthreads();
      {
        const int row = tid >> 5, col = tid & 31;
        const size_t g = rowbase + (size_t)row * 1024 + (size_t)(c * 256 + col * 8);
        const size_t l = (size_t)row * 264 + (size_t)(col * 8);
        if (do_h0)           *(uint4*)&sa[0 * 8448 + l] = *(const uint4*)&xh[g];
        if (do_h0 && do_rec) *(uint4*)&sa[1 * 8448 + l] = *(const uint4*)&thh[g];
        if (do_rec)          *(uint4*)&sa[2 * 8448 + l] = *(const uint4*)&h1h[g];
      }
      __syncthreads();
      const int koff = c * 256 + ks * 8;
      const int al = b5 * 264 + ks * 8;
      uint4 xa = {}, ta = {}, ha = {};
      if (do_h0)           xa = *(const uint4*)&sa[0 * 8448 + al];
      if (do_h0 && do_rec) ta = *(const uint4*)&sa[1 * 8448 + al];
      if (do_rec)          ha = *(const uint4*)&sa[2 * 8448 + al];
#pragma unroll
      for (int j = 0; j < 8; ++j) {
        if (do_h0) {
          const uint4 w = *(const uint4*)&Wl[(0 * 8 + j) * 1032 + koff];
          acc0[j] = fdot2(xa.x, w.x, acc0[j]);
          acc0[j] = fdot2(xa.y, w.y, acc0[j]);
          acc0[j] = fdot2(xa.z, w.z, acc0[j]);
          acc0[j] = fdot2(xa.w, w.w, acc0[j]);
          if (do_rec) {
            const uint4 w1 = *(const uint4*)&Wl[(1 * 8 + j) * 1032 + koff];
            acc0[j] = fdot2(ta.x, w1.x, acc0[j]);
            acc0[j] = fdot2(ta.y, w1.y, acc0[j]);
            acc0[j] = fdot2(ta.z, w1.z, acc0[j]);
            acc0[j] = fdot2(ta.w, w1.w, acc0[j]);
          }
        }
        if (do_rec) {
          const uint4 w4 = *(const uint4*)&Wl[(4 * 8 + j) * 1032 + koff];
          acc1[j] = fdot2(ha.x, w4.x, acc1[j]);
          acc1[j] = fdot2(ha.y, w4.y, acc1[j]);
          acc1[j] = fdot2(ha.z, w4.z, acc1[j]);
          acc1[j] = fdot2(ha.w, w4.w, acc1[j]);
        }
      }
    }
    __syncthreads();
#pragma unroll
    for (int j = 0; j < 8; ++j) {
      acc0[j] += __shfl_xor(acc0[j], 32);
      acc1[j] += __shfl_xor(acc1[j], 32);
    }
    if ((ks & 1) == 0) {
      const int kh = ks >> 1;
#pragma unroll
      for (int j = 0; j < 8; ++j) {
        sr[(j * 16 + kh) * 32 + b5] = acc0[j];
        sr[4096 + (j * 16 + kh) * 32 + b5] = acc1[j];
      }
    }
    __syncthreads();
    if (tid < 256) {
      const int j = tid >> 5, bb = tid & 31;
      const int gj = js * 8 + j;
      const int gb = bg * 32 + bb;
      float s0 = 0.f, s1 = 0.f;
#pragma unroll
      for (int kh = 0; kh < 16; ++kh) {
        s0 += sr[(j * 16 + kh) * 32 + bb];
        s1 += sr[4096 + (j * 16 + kh) * 32 + bb];
      }
      if (do_h0) {
        const float v = s0 + bias_b0;
        const float tv = tanhf(v);
        h0h[(size_t)gb * 1024 + gj] = (f16)v;
        th0h[(size_t)gb * 1024 + gj] = (f16)tv;
      }
      if (do_rec) {
        dout[(size_t)(t - 1) * SLOT + (size_t)gb * 1024 + gj] = s1 + bias_bo1;
      }
    }
    gbar(flags, gen, wg, ++ph);

    if (do_h0) {
      float accB[8] = {0,0,0,0,0,0,0,0};
      for (int c = 0; c < 4; ++c) {
        __syncthreads();
        {
          const int row = tid >> 5, col = tid & 31;
          const size_t g = rowbase + (size_t)row * 1024 + (size_t)(c * 256 + col * 8);
          const size_t l = (size_t)row * 264 + (size_t)(col * 8);
          *(uint4*)&sa[0 * 8448 + l] = *(const uint4*)&h0h[g];
          *(uint4*)&sa[1 * 8448 + l] = *(const uint4*)&th0h[g];
        }
        __syncthreads();
        const int koff = c * 256 + ks * 8;
        const int al = b5 * 264 + ks * 8;
        const uint4 h0a = *(const uint4*)&sa[0 * 8448 + al];
        const uint4 t0a = *(const uint4*)&sa[1 * 8448 + al];
#pragma unroll
        for (int j = 0; j < 8; ++j) {
          const uint4 wm = *(const uint4*)&Wl[(2 * 8 + j) * 1032 + koff];
          accB[j] = fdot2(h0a.x, wm.x, accB[j]);
          accB[j] = fdot2(h0a.y, wm.y, accB[j]);
          accB[j] = fdot2(h0a.z, wm.z, accB[j]);
          accB[j] = fdot2(h0a.w, wm.w, accB[j]);
          const uint4 wh = *(const uint4*)&Wl[(3 * 8 + j) * 1032 + koff];
          accB[j] = fdot2(t0a.x, wh.x, accB[j]);
          accB[j] = fdot2(t0a.y, wh.y, accB[j]);
          accB[j] = fdot2(t0a.z, wh.z, accB[j]);
          accB[j] = fdot2(t0a.w, wh.w, accB[j]);
        }
      }
      __syncthreads();
#pragma unroll
      for (int j = 0; j < 8; ++j) accB[j] += __shfl_xor(accB[j], 32);
      if ((ks & 1) == 0) {
        const int kh = ks >> 1;
#pragma unroll
        for (int j = 0; j < 8; ++j) sr[(j * 16 + kh) * 32 + b5] = accB[j];
      }
      __syncthreads();
      if (tid < 256) {
        const int j = tid >> 5, bb = tid & 31;
        const int gj = js * 8 + j;
        const int gb = bg * 32 + bb;
        float v = 0.f;
#pragma unroll
        for (int kh = 0; kh < 16; ++kh) v += sr[(j * 16 + kh) * 32 + bb];
        v += bias_c1;
        const float tv = tanhf(v);
        h1h[(size_t)gb * 1024 + gj] = (f16)v;
        thh[(size_t)gb * 1024 + gj] = (f16)tv;
        dout[FINALOFF + (size_t)gb * 1024 + gj] = tv;
      }
      gbar(flags, gen, wg, ++ph);
    }
  }
}

extern "C" void kernel_launch(void* const* d_in, const int* in_sizes, int n_in,
                              void* d_out, int out_size, void* d_ws, size_t ws_size,
                              hipStream_t stream) {
  (void)in_sizes; (void)n_in; (void)out_size; (void)ws_size;
  const float* x  = (const float*)d_in[0];
  const float* Wi = (const float*)d_in[1];
  const float* bi = (const float*)d_in[2];
  const float* Wh = (const float*)d_in[3];
  const float* bh = (const float*)d_in[4];
  const float* Wo = (const float*)d_in[5];
  const float* bo = (const float*)d_in[6];
  char* ws = (char*)d_ws;
  float* out = (float*)d_out;

  k_init<<<1, 512, 0, stream>>>((unsigned int*)(ws + OFF_FLAGS));
  k_bias_c1<<<4, 256, 0, stream>>>(Wi, bi, bh, bo, (float*)(ws + OFF_B0), (float*)(ws + OFF_C1));
  k_gemm_M<<<256, 256, 0, stream>>>(Wi, Wo, (f16*)(ws + OFF_M));
  k_convert_x<<<32768, 256, 0, stream>>>(x, out);
  k_rnn<<<NWG, 1024, 0, stream>>>(Wi, Wh, Wo, bo, ws, out);
}

// Round 2
// 10172.654 us; speedup vs baseline: 10.4870x; 10.4870x over previous
//
#include <hip/hip_runtime.h>
#include <cstdint>
#include <cstddef>

#define TT   512
#define NWG  256
#define SLOT 65536            // floats per timestep slot in d_out
#define SLOTB 262144          // bytes per slot
#define FINALOFF ((size_t)TT * (size_t)SLOT)

// ws layout (bytes)
#define OFF_M     0                         // M fp16: 2 MiB
#define OFF_H0    2097152                   // 64*1024 f16
#define OFF_TH0   (OFF_H0 + 131072)
#define OFF_H1A   (OFF_TH0 + 131072)
#define OFF_H1B   (OFF_H1A + 131072)
#define OFF_TH    (OFF_H1B + 131072)
#define OFF_B0    (OFF_TH + 131072)         // 1024 f32
#define OFF_C1    (OFF_B0 + 4096)           // 1024 f32
#define OFF_FLAGS (OFF_C1 + 4096)           // 512 uints (flags[0..255], gen at [320])

typedef _Float16 f16;
typedef unsigned long long ull;
typedef _Float16 h2 __attribute__((ext_vector_type(2)));

#if __has_builtin(__builtin_amdgcn_fdot2)
__device__ __forceinline__ float fdot2(unsigned int a, unsigned int w, float c) {
  return __builtin_amdgcn_fdot2(__builtin_bit_cast(h2, a), __builtin_bit_cast(h2, w), c, false);
}
#else
__device__ __forceinline__ float fdot2(unsigned int a, unsigned int w, float c) {
  h2 ha = __builtin_bit_cast(h2, a), hw = __builtin_bit_cast(h2, w);
  return c + (float)ha.x * (float)hw.x + (float)ha.y * (float)hw.y;
}
#endif

// relaxed agent-scope (sc1: bypass non-coherent per-XCD L2) 8B access helpers
__device__ __forceinline__ void st8(void* p, ull v) {
  __hip_atomic_store((ull*)p, v, __ATOMIC_RELAXED, __HIP_MEMORY_SCOPE_AGENT);
}
__device__ __forceinline__ ull ld8(const void* p) {
  return __hip_atomic_load((const ull*)p, __ATOMIC_RELAXED, __HIP_MEMORY_SCOPE_AGENT);
}

__global__ void k_init(unsigned int* flags) {
  flags[threadIdx.x] = 0u;  // 512 threads cover flags + gen
}

// c1[i] = sum_k Wi1[i,k]*bo0[k] + bi1[i] + bh1[i];  b0[i] = bi0[i] + bh0[i]
__global__ void k_bias_c1(const float* __restrict__ Wi, const float* __restrict__ bi,
                          const float* __restrict__ bh, const float* __restrict__ bo,
                          float* __restrict__ b0, float* __restrict__ c1) {
  const int i = blockIdx.x * 256 + threadIdx.x;
  const float* row = Wi + 1048576 + (size_t)i * 1024;
  float s = 0.f;
  for (int k = 0; k < 1024; k += 4) {
    const float4 w = *(const float4*)&row[k];
    const float4 v = *(const float4*)&bo[k];
    s += w.x * v.x + w.y * v.y + w.z * v.z + w.w * v.w;
  }
  c1[i] = s + bi[1024 + i] + bh[1024 + i];
  b0[i] = bi[i] + bh[i];
}

// M[i][d] = sum_k Wi1[i][k] * Wo0[k][d]   (fp32 compute, fp16 store)
__global__ __launch_bounds__(256) void k_gemm_M(const float* __restrict__ Wi,
                                                const float* __restrict__ Wo,
                                                f16* __restrict__ Mh) {
  const float* A = Wi + 1048576;  // [i][k]
  const float* B = Wo;            // [k][d]
  __shared__ float As[16][68];
  __shared__ float Bs[16][68];
  const int bi = blockIdx.x >> 4, bj = blockIdx.x & 15;
  const int i0 = bi * 64, d0 = bj * 64;
  const int ti = threadIdx.x >> 4, tj = threadIdx.x & 15;
  float acc[4][4] = {};
  for (int kc = 0; kc < 1024; kc += 16) {
    const int r = threadIdx.x >> 2, cg = (threadIdx.x & 3) << 2;
    const float4 av = *(const float4*)&A[(size_t)(i0 + r) * 1024 + kc + cg];
    As[cg + 0][r] = av.x; As[cg + 1][r] = av.y; As[cg + 2][r] = av.z; As[cg + 3][r] = av.w;
    const int c2 = threadIdx.x >> 4, dg = (threadIdx.x & 15) << 2;
    const float4 bv = *(const float4*)&B[(size_t)(kc + c2) * 1024 + d0 + dg];
    *(float4*)&Bs[c2][dg] = bv;
    __syncthreads();
#pragma unroll
    for (int kk = 0; kk < 16; ++kk) {
      float a[4], b[4];
#pragma unroll
      for (int q = 0; q < 4; ++q) { a[q] = As[kk][ti * 4 + q]; b[q] = Bs[kk][tj * 4 + q]; }
#pragma unroll
      for (int p = 0; p < 4; ++p)
#pragma unroll
        for (int q = 0; q < 4; ++q) acc[p][q] += a[p] * b[q];
    }
    __syncthreads();
  }
#pragma unroll
  for (int p = 0; p < 4; ++p)
#pragma unroll
    for (int q = 0; q < 4; ++q)
      Mh[(size_t)(i0 + ti * 4 + p) * 1024 + (size_t)(d0 + tj * 4 + q)] = (f16)acc[p][q];
}

// x (fp32) -> fp16 copies stored in the first half of each d_out timestep slot
__global__ void k_convert_x(const float* __restrict__ x, float* __restrict__ dout) {
  const size_t idx4 = (size_t)blockIdx.x * 256 + threadIdx.x;
  const int t = (int)(idx4 >> 14);
  const int r = (int)(idx4 & 16383);
  const float4 v = ((const float4*)x)[idx4];
  f16* dst = (f16*)((char*)dout + (size_t)t * SLOTB) + (size_t)r * 4;
  dst[0] = (f16)v.x; dst[1] = (f16)v.y; dst[2] = (f16)v.z; dst[3] = (f16)v.w;
}

// ---- grid barrier, split arrive/wait; relaxed spins, no cache maintenance ----
__device__ __forceinline__ void gbar_arrive(unsigned int* flags, unsigned int* gen,
                                            int wg, unsigned int ph) {
  asm volatile("s_waitcnt vmcnt(0)" ::: "memory");   // drain this thread's sc1 stores
  __syncthreads();
  if (wg == 0) {
    const int tt = threadIdx.x;
    if (tt > 0 && tt < NWG) {
      while (__hip_atomic_load(&flags[tt], __ATOMIC_RELAXED, __HIP_MEMORY_SCOPE_AGENT) < ph)
        __builtin_amdgcn_s_sleep(1);
    }
    __syncthreads();
    if (tt == 0)
      __hip_atomic_store(gen, ph, __ATOMIC_RELAXED, __HIP_MEMORY_SCOPE_AGENT);
  } else {
    if (threadIdx.x == 0)
      __hip_atomic_store(&flags[wg], ph, __ATOMIC_RELAXED, __HIP_MEMORY_SCOPE_AGENT);
  }
}
__device__ __forceinline__ void gbar_wait(unsigned int* flags, unsigned int* gen,
                                          int wg, unsigned int ph) {
  if (wg != 0) {
    if (threadIdx.x == 0) {
      while (__hip_atomic_load(gen, __ATOMIC_RELAXED, __HIP_MEMORY_SCOPE_AGENT) < ph)
        __builtin_amdgcn_s_sleep(1);
    }
    __syncthreads();
  }
  asm volatile("" ::: "memory");
}

// ---- persistent RNN loop ----
// phase A(t) crit: h0 = Wi0*x[t] + Wh0*th + b0
// between barriers: outs[t-1] = Wo1*h1 + bo1   (off critical path)
// phase B(t): h1 = M*h0 + Wh1*th0 + c1 ; th = tanh(h1)
__global__ __launch_bounds__(1024, 4) void k_rnn(
    const float* __restrict__ Wi, const float* __restrict__ Wh,
    const float* __restrict__ Wo, const float* __restrict__ bo,
    char* __restrict__ ws, float* __restrict__ dout)
{
  const f16* Mh  = (const f16*)(ws + OFF_M);
  f16* h0h  = (f16*)(ws + OFF_H0);
  f16* th0h = (f16*)(ws + OFF_TH0);
  f16* h1A  = (f16*)(ws + OFF_H1A);
  f16* h1B  = (f16*)(ws + OFF_H1B);
  f16* thh  = (f16*)(ws + OFF_TH);
  const float* b0p = (const float*)(ws + OFF_B0);
  const float* c1p = (const float*)(ws + OFF_C1);
  unsigned int* flags = (unsigned int*)(ws + OFF_FLAGS);
  unsigned int* gen = flags + 320;

  const int wg = blockIdx.x;
  const int bg = wg & 1;
  const int js = wg >> 1;
  const int tid = threadIdx.x;
  const int b5 = tid & 31;
  const int ks = tid >> 5;  // 0..31 (K split)

  __shared__ __align__(16) f16 Wl[5 * 8 * 1032];   // 5 mats x 8 rows, padded stride
  __shared__ __align__(16) char shbuf[50688];      // act chunks / reduction (overlaid)
  f16* sa = (f16*)shbuf;                 // sa0 @0, sa1 @8448, sa2 @16896 (f16 idx)
  float* sr = (float*)shbuf;             // reduce buffer, floats [0..4096)
  f16* tr0 = (f16*)(shbuf + 33792);      // transpose store buffers (sa2 region, sequenced)
  f16* tr1 = tr0 + 256;
  float* trf = (float*)(shbuf + 33792 + 1024);

  // load + convert this WG's weight rows into LDS (mats: 0 Wi0, 1 Wh0, 2 M, 3 Wh1, 4 Wo1)
  for (int u = tid; u < 5 * 2048; u += 1024) {
    const int m = u >> 11;
    const int rr = (u >> 8) & 7;
    const int cc = (u & 255) << 2;
    const int grow = js * 8 + rr;
    f16* dst = &Wl[(m * 8 + rr) * 1032 + cc];
    if (m == 2) {
      *(uint2*)dst = *(const uint2*)&Mh[(size_t)grow * 1024 + cc];
    } else {
      const float* s = (m == 0) ? Wi : (m == 1) ? Wh : (m == 3) ? (Wh + 1048576) : (Wo + 1048576);
      const float4 v = *(const float4*)&s[(size_t)grow * 1024 + cc];
      dst[0] = (f16)v.x; dst[1] = (f16)v.y; dst[2] = (f16)v.z; dst[3] = (f16)v.w;
    }
  }
  float bias_b0 = 0.f, bias_c1 = 0.f, bias_bo1 = 0.f;
  if (tid < 256) {
    const int gj = js * 8 + (tid >> 5);
    bias_b0 = b0p[gj]; bias_c1 = c1p[gj]; bias_bo1 = bo[1024 + gj];
  }
  __syncthreads();

  const size_t rowbase = (size_t)(bg * 32) * 1024;
  const int row = tid >> 5, col = tid & 31;
  const size_t gbase = rowbase + (size_t)row * 1024 + (size_t)(col * 8);
  const size_t lbase = (size_t)row * 264 + (size_t)(col * 8);
  const int koff0 = ks * 8;
  const int al = b5 * 264 + ks * 8;
  unsigned int ph = 0;

  for (int t = 0; t <= TT; ++t) {
    const bool do_h0 = (t < TT);
    const bool do_rec = (t > 0);
    const f16* xh = (const f16*)((const char*)dout + (size_t)t * SLOTB);

    // ---------- phase A critical: acc0 = Wi0*x + Wh0*th ----------
    if (do_h0) {
      float acc0[8] = {0,0,0,0,0,0,0,0};
      uint4 xv; ull tv0 = 0, tv1 = 0;
      xv = *(const uint4*)&xh[gbase];
      if (do_rec) { tv0 = ld8(&thh[gbase]); tv1 = ld8(&thh[gbase + 4]); }
      for (int c = 0; c < 4; ++c) {
        __syncthreads();
        *(uint4*)&sa[lbase] = xv;
        if (do_rec) { ((ull*)&sa[8448 + lbase])[0] = tv0; ((ull*)&sa[8448 + lbase])[1] = tv1; }
        if (c < 3) {
          const size_t g = gbase + (size_t)((c + 1) * 256);
          xv = *(const uint4*)&xh[g];
          if (do_rec) { tv0 = ld8(&thh[g]); tv1 = ld8(&thh[g + 4]); }
        }
        __syncthreads();
        const int koff = c * 256 + koff0;
        const uint4 xa = *(const uint4*)&sa[al];
        uint4 ta = {0, 0, 0, 0};
        if (do_rec) ta = *(const uint4*)&sa[8448 + al];
#pragma unroll
        for (int j = 0; j < 8; ++j) {
          const uint4 w = *(const uint4*)&Wl[(0 * 8 + j) * 1032 + koff];
          acc0[j] = fdot2(xa.x, w.x, acc0[j]);
          acc0[j] = fdot2(xa.y, w.y, acc0[j]);
          acc0[j] = fdot2(xa.z, w.z, acc0[j]);
          acc0[j] = fdot2(xa.w, w.w, acc0[j]);
          if (do_rec) {
            const uint4 w1 = *(const uint4*)&Wl[(1 * 8 + j) * 1032 + koff];
            acc0[j] = fdot2(ta.x, w1.x, acc0[j]);
            acc0[j] = fdot2(ta.y, w1.y, acc0[j]);
            acc0[j] = fdot2(ta.z, w1.z, acc0[j]);
            acc0[j] = fdot2(ta.w, w1.w, acc0[j]);
          }
        }
      }
      __syncthreads();
#pragma unroll
      for (int j = 0; j < 8; ++j) acc0[j] += __shfl_xor(acc0[j], 32);
      if ((ks & 1) == 0) {
        const int kh = ks >> 1;
#pragma unroll
        for (int j = 0; j < 8; ++j) sr[(j * 16 + kh) * 32 + b5] = acc0[j];
      }
      __syncthreads();
      if (tid < 256) {
        const int j = tid >> 5, bb = tid & 31;
        float s0 = 0.f;
#pragma unroll
        for (int kh = 0; kh < 16; ++kh) s0 += sr[(j * 16 + kh) * 32 + bb];
        const float v = s0 + bias_b0;
        const float tv = tanhf(v);
        tr0[bb * 8 + j] = (f16)v;
        tr1[bb * 8 + j] = (f16)tv;
      }
      __syncthreads();
      if (tid < 32) {
        f16* dst = &h0h[(size_t)(bg * 32 + tid) * 1024 + js * 8];
        st8(dst, ((const ull*)tr0)[tid * 2]);
        st8(dst + 4, ((const ull*)tr0)[tid * 2 + 1]);
      } else if (tid < 64) {
        const int u = tid - 32;
        f16* dst = &th0h[(size_t)(bg * 32 + u) * 1024 + js * 8];
        st8(dst, ((const ull*)tr1)[u * 2]);
        st8(dst + 4, ((const ull*)tr1)[u * 2 + 1]);
      }
    }
    gbar_arrive(flags, gen, wg, ++ph);

    // ---------- deferred out-GEMM (overlaps barrier): outs[t-1] = Wo1*h1 + bo1 ----------
    if (do_rec) {
      const f16* h1src = ((t - 1) & 1) ? h1B : h1A;
      float acc1[8] = {0,0,0,0,0,0,0,0};
      ull hv0 = ld8(&h1src[gbase]), hv1 = ld8(&h1src[gbase + 4]);
      for (int c = 0; c < 4; ++c) {
        __syncthreads();
        ((ull*)&sa[16896 + lbase])[0] = hv0; ((ull*)&sa[16896 + lbase])[1] = hv1;
        if (c < 3) {
          const size_t g = gbase + (size_t)((c + 1) * 256);
          hv0 = ld8(&h1src[g]); hv1 = ld8(&h1src[g + 4]);
        }
        __syncthreads();
        const int koff = c * 256 + koff0;
        const uint4 ha = *(const uint4*)&sa[16896 + al];
#pragma unroll
        for (int j = 0; j < 8; ++j) {
          const uint4 w4 = *(const uint4*)&Wl[(4 * 8 + j) * 1032 + koff];
          acc1[j] = fdot2(ha.x, w4.x, acc1[j]);
          acc1[j] = fdot2(ha.y, w4.y, acc1[j]);
          acc1[j] = fdot2(ha.z, w4.z, acc1[j]);
          acc1[j] = fdot2(ha.w, w4.w, acc1[j]);
        }
      }
      __syncthreads();
#pragma unroll
      for (int j = 0; j < 8; ++j) acc1[j] += __shfl_xor(acc1[j], 32);
      if ((ks & 1) == 0) {
        const int kh = ks >> 1;
#pragma unroll
        for (int j = 0; j < 8; ++j) sr[(j * 16 + kh) * 32 + b5] = acc1[j];
      }
      __syncthreads();
      if (tid < 256) {
        const int j = tid >> 5, bb = tid & 31;
        float s1 = 0.f;
#pragma unroll
        for (int kh = 0; kh < 16; ++kh) s1 += sr[(j * 16 + kh) * 32 + bb];
        trf[bb * 8 + j] = s1 + bias_bo1;
      }
      __syncthreads();
      if (tid >= 64 && tid < 192) {
        const int u = tid - 64, bb = u >> 2, q = u & 3;
        st8(&dout[(size_t)(t - 1) * SLOT + (size_t)(bg * 32 + bb) * 1024 + js * 8 + q * 2],
            ((const ull*)trf)[bb * 4 + q]);
      }
    }
    gbar_wait(flags, gen, wg, ph);

    // ---------- phase B: h1 = M*h0 + Wh1*th0 + c1 ; th = tanh(h1) ----------
    if (do_h0) {
      f16* h1dst = (t & 1) ? h1B : h1A;
      float accB[8] = {0,0,0,0,0,0,0,0};
      ull a0 = ld8(&h0h[gbase]), a1 = ld8(&h0h[gbase + 4]);
      ull c0 = ld8(&th0h[gbase]), c1v = ld8(&th0h[gbase + 4]);
      for (int c = 0; c < 4; ++c) {
        __syncthreads();
        ((ull*)&sa[lbase])[0] = a0; ((ull*)&sa[lbase])[1] = a1;
        ((ull*)&sa[8448 + lbase])[0] = c0; ((ull*)&sa[8448 + lbase])[1] = c1v;
        if (c < 3) {
          const size_t g = gbase + (size_t)((c + 1) * 256);
          a0 = ld8(&h0h[g]); a1 = ld8(&h0h[g + 4]);
          c0 = ld8(&th0h[g]); c1v = ld8(&th0h[g + 4]);
        }
        __syncthreads();
        const int koff = c * 256 + koff0;
        const uint4 h0a = *(const uint4*)&sa[al];
        const uint4 t0a = *(const uint4*)&sa[8448 + al];
#pragma unroll
        for (int j = 0; j < 8; ++j) {
          const uint4 wm = *(const uint4*)&Wl[(2 * 8 + j) * 1032 + koff];
          accB[j] = fdot2(h0a.x, wm.x, accB[j]);
          accB[j] = fdot2(h0a.y, wm.y, accB[j]);
          accB[j] = fdot2(h0a.z, wm.z, accB[j]);
          accB[j] = fdot2(h0a.w, wm.w, accB[j]);
          const uint4 wh = *(const uint4*)&Wl[(3 * 8 + j) * 1032 + koff];
          accB[j] = fdot2(t0a.x, wh.x, accB[j]);
          accB[j] = fdot2(t0a.y, wh.y, accB[j]);
          accB[j] = fdot2(t0a.z, wh.z, accB[j]);
          accB[j] = fdot2(t0a.w, wh.w, accB[j]);
        }
      }
      __syncthreads();
#pragma unroll
      for (int j = 0; j < 8; ++j) accB[j] += __shfl_xor(accB[j], 32);
      if ((ks & 1) == 0) {
        const int kh = ks >> 1;
#pragma unroll
        for (int j = 0; j < 8; ++j) sr[(j * 16 + kh) * 32 + b5] = accB[j];
      }
      __syncthreads();
      if (tid < 256) {
        const int j = tid >> 5, bb = tid & 31;
        float v = 0.f;
#pragma unroll
        for (int kh = 0; kh < 16; ++kh) v += sr[(j * 16 + kh) * 32 + bb];
        v += bias_c1;
        const float tv = tanhf(v);
        tr0[bb * 8 + j] = (f16)v;
        tr1[bb * 8 + j] = (f16)tv;
        if (t == TT - 1) trf[bb * 8 + j] = tv;
      }
      __syncthreads();
      if (tid < 32) {
        f16* dst = &h1dst[(size_t)(bg * 32 + tid) * 1024 + js * 8];
        st8(dst, ((const ull*)tr0)[tid * 2]);
        st8(dst + 4, ((const ull*)tr0)[tid * 2 + 1]);
      } else if (tid < 64) {
        const int u = tid - 32;
        f16* dst = &thh[(size_t)(bg * 32 + u) * 1024 + js * 8];
        st8(dst, ((const ull*)tr1)[u * 2]);
        st8(dst + 4, ((const ull*)tr1)[u * 2 + 1]);
      }
      if (t == TT - 1 && tid >= 64 && tid < 192) {
        const int u = tid - 64, bb = u >> 2, q = u & 3;
        st8(&dout[FINALOFF + (size_t)(bg * 32 + bb) * 1024 + js * 8 + q * 2],
            ((const ull*)trf)[bb * 4 + q]);
      }
      gbar_arrive(flags, gen, wg, ++ph);
      gbar_wait(flags, gen, wg, ph);
    }
  }
}

extern "C" void kernel_launch(void* const* d_in, const int* in_sizes, int n_in,
                              void* d_out, int out_size, void* d_ws, size_t ws_size,
                              hipStream_t stream) {
  (void)in_sizes; (void)n_in; (void)out_size; (void)ws_size;
  const float* x  = (const float*)d_in[0];
  const float* Wi = (const float*)d_in[1];
  const float* bi = (const float*)d_in[2];
  const float* Wh = (const float*)d_in[3];
  const float* bh = (const float*)d_in[4];
  const float* Wo = (const float*)d_in[5];
  const float* bo = (const float*)d_in[6];
  char* ws = (char*)d_ws;
  float* out = (float*)d_out;

  k_init<<<1, 512, 0, stream>>>((unsigned int*)(ws + OFF_FLAGS));
  k_bias_c1<<<4, 256, 0, stream>>>(Wi, bi, bh, bo, (float*)(ws + OFF_B0), (float*)(ws + OFF_C1));
  k_gemm_M<<<256, 256, 0, stream>>>(Wi, Wo, (f16*)(ws + OFF_M));
  k_convert_x<<<32768, 256, 0, stream>>>(x, out);
  k_rnn<<<NWG, 1024, 0, stream>>>(Wi, Wh, Wo, bo, ws, out);
}

// Round 3
// 6034.317 us; speedup vs baseline: 17.6791x; 1.6858x over previous
//
#include <hip/hip_runtime.h>
#include <cstdint>
#include <cstddef>

#define TT   512
#define NWG  256
#define SLOT 65536            // floats per timestep slot in d_out
#define SLOTB 262144          // bytes per slot
#define FINALOFF ((size_t)TT * (size_t)SLOT)

// ws layout (bytes)
#define OFF_M     0                         // M f16: 2 MiB
#define OFF_H0    2097152                   // 64*1024 f16
#define OFF_H1    (OFF_H0 + 131072)
#define OFF_C1    (OFF_H1 + 131072)         // 1024 f32
#define OFF_FLAGS (OFF_C1 + 4096)           // 512 uints (flags[0..255], gen at [320])

typedef _Float16 f16;
typedef unsigned long long ull;
typedef _Float16 v8h __attribute__((ext_vector_type(8)));
typedef float v4f __attribute__((ext_vector_type(4)));

union U2 { ull u[2]; v8h v; };

__device__ __forceinline__ void st8(void* p, ull v) {
  __hip_atomic_store((ull*)p, v, __ATOMIC_RELAXED, __HIP_MEMORY_SCOPE_AGENT);
}
__device__ __forceinline__ ull ld8(const void* p) {
  return __hip_atomic_load((const ull*)p, __ATOMIC_RELAXED, __HIP_MEMORY_SCOPE_AGENT);
}

__device__ __forceinline__ float rcpf(float x) {
#if __has_builtin(__builtin_amdgcn_rcpf)
  return __builtin_amdgcn_rcpf(x);
#else
  return 1.0f / x;
#endif
}
__device__ __forceinline__ float tanhfast(float x) {
  x = fminf(fmaxf(x, -20.0f), 20.0f);
  const float u = __expf(-2.0f * x);
  return 1.0f - 2.0f * u * rcpf(1.0f + u);
}
__device__ __forceinline__ v8h tanh8(v8h h) {
  v8h r;
#pragma unroll
  for (int i = 0; i < 8; ++i) r[i] = (f16)tanhfast((float)h[i]);
  return r;
}

__global__ void k_init(unsigned int* flags) {
  flags[threadIdx.x] = 0u;  // 512 threads cover flags + gen
}

// c1[i] = sum_k Wi1[i,k]*bo0[k] + bi1[i] + bh1[i]
__global__ void k_bias_c1(const float* __restrict__ Wi, const float* __restrict__ bi,
                          const float* __restrict__ bh, const float* __restrict__ bo,
                          float* __restrict__ c1) {
  const int i = blockIdx.x * 256 + threadIdx.x;
  const float* row = Wi + 1048576 + (size_t)i * 1024;
  float s = 0.f;
  for (int k = 0; k < 1024; k += 4) {
    const float4 w = *(const float4*)&row[k];
    const float4 v = *(const float4*)&bo[k];
    s += w.x * v.x + w.y * v.y + w.z * v.z + w.w * v.w;
  }
  c1[i] = s + bi[1024 + i] + bh[1024 + i];
}

// M[i][d] = sum_k Wi1[i][k] * Wo0[k][d]   (fp32 compute, f16 store)
__global__ __launch_bounds__(256) void k_gemm_M(const float* __restrict__ Wi,
                                                const float* __restrict__ Wo,
                                                f16* __restrict__ Mh) {
  const float* A = Wi + 1048576;  // [i][k]
  const float* B = Wo;            // [k][d]
  __shared__ float As[16][68];
  __shared__ float Bs[16][68];
  const int bi = blockIdx.x >> 4, bj = blockIdx.x & 15;
  const int i0 = bi * 64, d0 = bj * 64;
  const int ti = threadIdx.x >> 4, tj = threadIdx.x & 15;
  float acc[4][4] = {};
  for (int kc = 0; kc < 1024; kc += 16) {
    const int r = threadIdx.x >> 2, cg = (threadIdx.x & 3) << 2;
    const float4 av = *(const float4*)&A[(size_t)(i0 + r) * 1024 + kc + cg];
    As[cg + 0][r] = av.x; As[cg + 1][r] = av.y; As[cg + 2][r] = av.z; As[cg + 3][r] = av.w;
    const int c2 = threadIdx.x >> 4, dg = (threadIdx.x & 15) << 2;
    const float4 bv = *(const float4*)&B[(size_t)(kc + c2) * 1024 + d0 + dg];
    *(float4*)&Bs[c2][dg] = bv;
    __syncthreads();
#pragma unroll
    for (int kk = 0; kk < 16; ++kk) {
      float a[4], b[4];
#pragma unroll
      for (int q = 0; q < 4; ++q) { a[q] = As[kk][ti * 4 + q]; b[q] = Bs[kk][tj * 4 + q]; }
#pragma unroll
      for (int p = 0; p < 4; ++p)
#pragma unroll
        for (int q = 0; q < 4; ++q) acc[p][q] += a[p] * b[q];
    }
    __syncthreads();
  }
#pragma unroll
  for (int p = 0; p < 4; ++p)
#pragma unroll
    for (int q = 0; q < 4; ++q)
      Mh[(size_t)(i0 + ti * 4 + p) * 1024 + (size_t)(d0 + tj * 4 + q)] = (f16)acc[p][q];
}

// x (fp32) -> f16 copies stored in the SECOND half of each d_out timestep slot
__global__ void k_convert_x(const float* __restrict__ x, float* __restrict__ dout) {
  const size_t idx4 = (size_t)blockIdx.x * 256 + threadIdx.x;
  const int t = (int)(idx4 >> 14);
  const int r = (int)(idx4 & 16383);
  const float4 v = ((const float4*)x)[idx4];
  f16* dst = (f16*)((char*)dout + (size_t)t * SLOTB + 131072) + (size_t)r * 4;
  dst[0] = (f16)v.x; dst[1] = (f16)v.y; dst[2] = (f16)v.z; dst[3] = (f16)v.w;
}

// z1(t) = x(t) . Wi0^T + b0  (f16, stored in FIRST half of each d_out slot)
// grid: 512 t * 16 jt; WG = 256 thr, 4 waves; wave covers 16 j, 64 b, K=1024
__global__ __launch_bounds__(256) void k_z1(const float* __restrict__ Wi,
                                            const float* __restrict__ bi,
                                            const float* __restrict__ bh,
                                            float* __restrict__ dout) {
  const int t = blockIdx.x >> 4, jt = blockIdx.x & 15;
  const int tid = threadIdx.x, l = tid & 63, w = tid >> 6;
  const int lj = l & 15, lk = l >> 4;
  const int jrow = jt * 64 + w * 16 + lj;
  const f16* xh = (const f16*)((const char*)dout + (size_t)t * SLOTB + 131072);
  v4f acc[4] = {{0.f,0.f,0.f,0.f},{0.f,0.f,0.f,0.f},{0.f,0.f,0.f,0.f},{0.f,0.f,0.f,0.f}};
  const float* wrow = Wi + (size_t)jrow * 1024;
  for (int ks = 0; ks < 32; ++ks) {
    const int k0 = ks * 32 + lk * 8;
    const float4 wa = *(const float4*)&wrow[k0];
    const float4 wb = *(const float4*)&wrow[k0 + 4];
    const v8h bf = {(f16)wa.x,(f16)wa.y,(f16)wa.z,(f16)wa.w,
                    (f16)wb.x,(f16)wb.y,(f16)wb.z,(f16)wb.w};
#pragma unroll
    for (int bt = 0; bt < 4; ++bt) {
      const v8h af = *(const v8h*)&xh[(size_t)(bt * 16 + lj) * 1024 + k0];
      acc[bt] = __builtin_amdgcn_mfma_f32_16x16x32_f16(af, bf, acc[bt], 0, 0, 0);
    }
  }
  const float bias = bi[jrow] + bh[jrow];
  f16* z = (f16*)((char*)dout + (size_t)t * SLOTB);
#pragma unroll
  for (int bt = 0; bt < 4; ++bt)
#pragma unroll
    for (int q = 0; q < 4; ++q)
      z[(size_t)(bt * 16 + lk * 4 + q) * 1024 + jrow] = (f16)(acc[bt][q] + bias);
}

// ---- grid barrier: arrive = flag store; wait = master collect + gen release ----
__device__ __forceinline__ void gbar_arrive(unsigned int* flags, int wg, unsigned int ph) {
  asm volatile("s_waitcnt vmcnt(0)" ::: "memory");
  __syncthreads();
  if (threadIdx.x == 0)
    __hip_atomic_store(&flags[wg], ph, __ATOMIC_RELAXED, __HIP_MEMORY_SCOPE_AGENT);
}
__device__ __forceinline__ void gbar_wait(unsigned int* flags, unsigned int* gen,
                                          int wg, unsigned int ph) {
  if (wg == 0) {
    const int tt = threadIdx.x;
    if (tt > 0 && tt < NWG)
      while (__hip_atomic_load(&flags[tt], __ATOMIC_RELAXED, __HIP_MEMORY_SCOPE_AGENT) < ph)
        __builtin_amdgcn_s_sleep(1);
    __syncthreads();
    if (tt == 0)
      __hip_atomic_store(gen, ph, __ATOMIC_RELAXED, __HIP_MEMORY_SCOPE_AGENT);
  } else {
    if (threadIdx.x == 0)
      while (__hip_atomic_load(gen, __ATOMIC_RELAXED, __HIP_MEMORY_SCOPE_AGENT) < ph)
        __builtin_amdgcn_s_sleep(1);
    __syncthreads();
  }
  asm volatile("" ::: "memory");
}

// ---- persistent RNN loop: weights in VGPRs, MFMA, only h0/h1 circulate ----
// phase A(t): h0 = z1(t) + Wh0*tanh(h1(t-1))        [h1 frags kept in regs]
// overlap   : outs[t-1] = Wo1*h1(t-1) + bo1          [reuses h1 frags]
// phase B(t): h1 = M*h0 + Wh1*tanh(h0) + c1
__global__ __launch_bounds__(256, 1) void k_rnn(
    const float* __restrict__ Wh, const float* __restrict__ Wo,
    const float* __restrict__ bo,
    char* __restrict__ ws, float* __restrict__ dout)
{
  const f16* Mh = (const f16*)(ws + OFF_M);
  f16* h0h = (f16*)(ws + OFF_H0);
  f16* h1h = (f16*)(ws + OFF_H1);
  const float* c1p = (const float*)(ws + OFF_C1);
  unsigned int* flags = (unsigned int*)(ws + OFF_FLAGS);
  unsigned int* gen = flags + 320;

  const int wg = blockIdx.x;
  const int bq = wg & 3;         // batch quadrant (16 rows)
  const int jt = wg >> 2;        // 0..63 (16 j cols)
  const int j0 = jt * 16;
  const int tid = threadIdx.x;
  const int l = tid & 63, w = tid >> 6;   // lane, wave (wave = K-slice of 256)
  const int lj = l & 15, lk = l >> 4;
  const int jrow = j0 + lj;

  __shared__ float red[1024];
  __shared__ f16 trh[256];
  __shared__ float trf[256];

  // ---- load weight fragments into registers (held for whole kernel) ----
  v8h wWh0[8], wM[8], wWh1[8], wWo1[8];
#pragma unroll
  for (int s = 0; s < 8; ++s) {
    const int k0 = w * 256 + s * 32 + lk * 8;
    {
      const float* p = &Wh[(size_t)jrow * 1024 + k0];
      float4 a = *(const float4*)p, b = *(const float4*)(p + 4);
      wWh0[s] = (v8h){(f16)a.x,(f16)a.y,(f16)a.z,(f16)a.w,(f16)b.x,(f16)b.y,(f16)b.z,(f16)b.w};
    }
    {
      const float* p = &Wh[1048576 + (size_t)jrow * 1024 + k0];
      float4 a = *(const float4*)p, b = *(const float4*)(p + 4);
      wWh1[s] = (v8h){(f16)a.x,(f16)a.y,(f16)a.z,(f16)a.w,(f16)b.x,(f16)b.y,(f16)b.z,(f16)b.w};
    }
    {
      const float* p = &Wo[1048576 + (size_t)jrow * 1024 + k0];
      float4 a = *(const float4*)p, b = *(const float4*)(p + 4);
      wWo1[s] = (v8h){(f16)a.x,(f16)a.y,(f16)a.z,(f16)a.w,(f16)b.x,(f16)b.y,(f16)b.z,(f16)b.w};
    }
    wM[s] = *(const v8h*)&Mh[(size_t)jrow * 1024 + k0];
  }
  const int rb = tid >> 4, rj = tid & 15;   // reducer's (b-in-tile, j-in-tile)
  const float c1v = c1p[j0 + rj];
  const float bo1v = bo[1024 + j0 + rj];

  const size_t actbase = (size_t)(bq * 16 + lj) * 1024 + (size_t)(w * 256 + lk * 8);
  unsigned int ph = 0;

  for (int t = 0; t <= TT; ++t) {
    const bool A = (t < TT), R = (t > 0);
    v8h hraw[8];

    // ---------- load h1(t-1) frags (used by phase A GEMM and out-GEMM) ----------
    if (R) {
      ull u0[8], u1[8];
#pragma unroll
      for (int s = 0; s < 8; ++s) {
        const f16* p = h1h + actbase + s * 32;
        u0[s] = ld8(p); u1[s] = ld8(p + 4);
      }
#pragma unroll
      for (int s = 0; s < 8; ++s) { U2 c; c.u[0] = u0[s]; c.u[1] = u1[s]; hraw[s] = c.v; }
    }

    // ---------- phase A: h0 = z1(t) + Wh0 * tanh(h1(t-1)) ----------
    if (A) {
      v4f acc = {0.f, 0.f, 0.f, 0.f};
      if (R) {
#pragma unroll
        for (int s = 0; s < 8; ++s)
          acc = __builtin_amdgcn_mfma_f32_16x16x32_f16(tanh8(hraw[s]), wWh0[s], acc, 0, 0, 0);
      }
#pragma unroll
      for (int q = 0; q < 4; ++q) red[w * 256 + (lk * 4 + q) * 16 + lj] = acc[q];
      __syncthreads();
      float h0 = red[tid] + red[256 + tid] + red[512 + tid] + red[768 + tid];
      const f16* z1 = (const f16*)((const char*)dout + (size_t)t * SLOTB);
      h0 += (float)z1[(size_t)(bq * 16 + rb) * 1024 + j0 + rj];
      trh[tid] = (f16)h0;
      __syncthreads();
      if (tid < 64)
        st8(&h0h[(size_t)(bq * 16 + (tid >> 2)) * 1024 + j0 + (tid & 3) * 4],
            ((const ull*)trh)[tid]);
    }
    gbar_arrive(flags, wg, ++ph);

    // ---------- deferred out-GEMM (overlaps barrier): outs[t-1] = Wo1*h1 + bo1 ----------
    if (R) {
      v4f a2 = {0.f, 0.f, 0.f, 0.f};
#pragma unroll
      for (int s = 0; s < 8; ++s)
        a2 = __builtin_amdgcn_mfma_f32_16x16x32_f16(hraw[s], wWo1[s], a2, 0, 0, 0);
#pragma unroll
      for (int q = 0; q < 4; ++q) red[w * 256 + (lk * 4 + q) * 16 + lj] = a2[q];
      __syncthreads();
      trf[tid] = red[tid] + red[256 + tid] + red[512 + tid] + red[768 + tid] + bo1v;
      __syncthreads();
      if (tid < 128)
        st8(&dout[(size_t)(t - 1) * SLOT + (size_t)(bq * 16 + (tid >> 3)) * 1024 + j0 + (tid & 7) * 2],
            ((const ull*)trf)[tid]);
    }
    gbar_wait(flags, gen, wg, ph);

    // ---------- phase B: h1 = M*h0 + Wh1*tanh(h0) + c1 ----------
    if (A) {
      ull g0[8], g1[8];
#pragma unroll
      for (int s = 0; s < 8; ++s) {
        const f16* p = h0h + actbase + s * 32;
        g0[s] = ld8(p); g1[s] = ld8(p + 4);
      }
      v4f aM = {0.f, 0.f, 0.f, 0.f}, aW = {0.f, 0.f, 0.f, 0.f};
#pragma unroll
      for (int s = 0; s < 8; ++s) {
        U2 c; c.u[0] = g0[s]; c.u[1] = g1[s];
        const v8h gv = c.v;
        aM = __builtin_amdgcn_mfma_f32_16x16x32_f16(gv, wM[s], aM, 0, 0, 0);
        aW = __builtin_amdgcn_mfma_f32_16x16x32_f16(tanh8(gv), wWh1[s], aW, 0, 0, 0);
      }
#pragma unroll
      for (int q = 0; q < 4; ++q) red[w * 256 + (lk * 4 + q) * 16 + lj] = aM[q] + aW[q];
      __syncthreads();
      const float h1 = red[tid] + red[256 + tid] + red[512 + tid] + red[768 + tid] + c1v;
      trh[tid] = (f16)h1;
      const bool last = (t == TT - 1);
      if (last) trf[tid] = tanhfast(h1);
      __syncthreads();
      if (tid < 64)
        st8(&h1h[(size_t)(bq * 16 + (tid >> 2)) * 1024 + j0 + (tid & 3) * 4],
            ((const ull*)trh)[tid]);
      if (last && tid < 128)
        st8(&dout[FINALOFF + (size_t)(bq * 16 + (tid >> 3)) * 1024 + j0 + (tid & 7) * 2],
            ((const ull*)trf)[tid]);
      gbar_arrive(flags, wg, ++ph);
      gbar_wait(flags, gen, wg, ph);
    }
  }
}

extern "C" void kernel_launch(void* const* d_in, const int* in_sizes, int n_in,
                              void* d_out, int out_size, void* d_ws, size_t ws_size,
                              hipStream_t stream) {
  (void)in_sizes; (void)n_in; (void)out_size; (void)ws_size;
  const float* x  = (const float*)d_in[0];
  const float* Wi = (const float*)d_in[1];
  const float* bi = (const float*)d_in[2];
  const float* Wh = (const float*)d_in[3];
  const float* bh = (const float*)d_in[4];
  const float* Wo = (const float*)d_in[5];
  const float* bo = (const float*)d_in[6];
  char* ws = (char*)d_ws;
  float* out = (float*)d_out;

  k_init<<<1, 512, 0, stream>>>((unsigned int*)(ws + OFF_FLAGS));
  k_convert_x<<<32768, 256, 0, stream>>>(x, out);
  k_bias_c1<<<4, 256, 0, stream>>>(Wi, bi, bh, bo, (float*)(ws + OFF_C1));
  k_gemm_M<<<256, 256, 0, stream>>>(Wi, Wo, (f16*)(ws + OFF_M));
  k_z1<<<8192, 256, 0, stream>>>(Wi, bi, bh, out);
  k_rnn<<<NWG, 256, 0, stream>>>(Wh, Wo, bo, ws, out);
}